// Round 1
// baseline (161.511 us; speedup 1.0000x reference)
//
#include <hip/hip_runtime.h>
#include <math.h>

#define B_   16
#define D_   512
#define T_   4096
#define CD   10
#define CS   1024
#define NTOK (B_*T_)          // 65536
#define TOK_PER_BLK 64
#define NBLK_MAIN  (NTOK/TOK_PER_BLK)  // 1024

// ws layout (float offsets)
#define WS_WIN    0            // 5120
#define WS_WOUT   5120         // 5120
#define WS_TABLE  10240        // 1024*512 = 524288
#define WS_PARTH  534528       // 1024
#define WS_PARTC  535552       // 1024
#define WS_HIST   536576       // 1024*1024
#define WS_HMID   1585152      // 32*1024

// ---------------------------------------------------------------- prep
__global__ __launch_bounds__(256) void prep_w(
    const float* __restrict__ in_v, const float* __restrict__ in_g,
    const float* __restrict__ out_v, const float* __restrict__ out_g,
    float* __restrict__ w_in, float* __restrict__ w_out)
{
  __shared__ float nrm[CD];
  int tid = threadIdx.x;
  if (tid < CD) {
    double s = 0.0;
    for (int D = 0; D < D_; ++D) { float v = in_v[tid*D_ + D]; s += (double)v * (double)v; }
    nrm[tid] = (float)sqrt(s);
  }
  __syncthreads();
  for (int i = tid; i < CD*D_; i += 256) {
    int d = i >> 9;                      // i = d*512 + D
    w_in[i] = in_g[d] * in_v[i] / nrm[d];
  }
  for (int r = tid; r < D_; r += 256) {
    float s = 0.f;
    #pragma unroll
    for (int d = 0; d < CD; ++d) { float v = out_v[r*CD + d]; s += v*v; }
    float sc = out_g[r] / sqrtf(s);
    #pragma unroll
    for (int d = 0; d < CD; ++d) w_out[r*CD + d] = out_v[r*CD + d] * sc;
  }
}

// Table[j][D] = out_b[D] + sum_d w_out[D][d] * (+-1 per bit (9-d) of j)
__global__ __launch_bounds__(512) void build_table(
    const float* __restrict__ w_out, const float* __restrict__ out_b,
    float* __restrict__ table)
{
  int j = blockIdx.x;
  int D = threadIdx.x;
  const float* wr = w_out + D*CD;
  float s = out_b[D];
  #pragma unroll
  for (int d = 0; d < CD; ++d) {
    float sg = ((j >> (9 - d)) & 1) ? 1.f : -1.f;
    s += wr[d] * sg;
  }
  table[(size_t)j*D_ + D] = s;
}

// ---------------------------------------------------------------- main
__global__ __launch_bounds__(256) void lfq_main(
    const float* __restrict__ x, const float* __restrict__ in_b,
    const float* __restrict__ w_in, const float* __restrict__ table,
    float* __restrict__ out, float* __restrict__ out_idx,
    float* __restrict__ partH, float* __restrict__ partC,
    float* __restrict__ hist_part)
{
  __shared__ float hist[CS];
  __shared__ int   sidx[TOK_PER_BLK];
  // union region, 33024 B: wT float[5120] | red double[2560] | rows float[64*129]
  __shared__ double uni[4128];
  float*  wT   = (float*)uni;
  double* red  = uni;
  float*  rows = (float*)uni;

  const int tid  = threadIdx.x;
  const int blk  = blockIdx.x;
  const int b    = blk >> 6;
  const int t0   = (blk & 63) * TOK_PER_BLK;
  const int wave = tid >> 6, lane = tid & 63;

  for (int i = tid; i < CS; i += 256) hist[i] = 0.f;
  for (int i = tid; i < CD*D_; i += 256) {
    // w_in is [d][D]; stage transposed wT[D][d]
    wT[(i & 511) * CD + (i >> 9)] = w_in[i];
  }
  __syncthreads();

  // phase A: in-projection, f64 accumulate. wave = D-slice, lane = token.
  double acc[CD];
  #pragma unroll
  for (int d = 0; d < CD; ++d) acc[d] = 0.0;
  const float* xb = x + ((size_t)b * D_) * T_ + t0 + lane;
  const int D0 = wave * 128;
  #pragma unroll 4
  for (int Di = 0; Di < 128; ++Di) {
    int D = D0 + Di;
    float  xv = xb[(size_t)D * T_];
    double xd = (double)xv;
    const float2* w2 = (const float2*)(wT + D * CD);
    #pragma unroll
    for (int i = 0; i < 5; ++i) {
      float2 w = w2[i];
      acc[2*i]   += (double)w.x * xd;
      acc[2*i+1] += (double)w.y * xd;
    }
  }
  __syncthreads();                   // done reading wT; reuse as red
  #pragma unroll
  for (int d = 0; d < CD; ++d) red[(wave*64 + lane)*CD + d] = acc[d];
  __syncthreads();

  // phase B: per-token quantize / entropy / histogram (wave 0 only)
  if (wave == 0) {
    float Hs = 0.f, C = 0.f;
    int   idx = 0;
    int   k = 0; int pos[CD]; float ms[CD];
    #pragma unroll
    for (int d = 0; d < CD; ++d) {
      double o = red[lane*CD + d] + red[(64+lane)*CD + d]
               + red[(128+lane)*CD + d] + red[(192+lane)*CD + d]
               + (double)in_b[d];
      float v = (float)o;
      int bit = (v > 0.f);
      idx |= bit << (9 - d);
      float c = v - (bit ? 1.f : -1.f);
      C += c * c;
      float e = __expf(-400.f * fabsf(v));   // exp(-|delta logit|)
      if (e > 1e-9f) { ms[k] = e / (1.f + e); pos[k] = 9 - d; ++k; }
    }
    int nc = 1 << k;
    for (int c = 0; c < nc; ++c) {
      float p = 1.f; int bin = idx;
      for (int i = 0; i < k; ++i) {
        if ((c >> i) & 1) { p *= ms[i]; bin ^= (1 << pos[i]); }
        else              { p *= (1.f - ms[i]); }
      }
      Hs -= p * __logf(fmaxf(p, 1e-5f));
      atomicAdd(&hist[bin], p);
    }
    out_idx[b * T_ + t0 + lane] = (float)idx;
    sidx[lane] = idx;
    #pragma unroll
    for (int off = 32; off > 0; off >>= 1) {
      Hs += __shfl_down(Hs, off, 64);
      C  += __shfl_down(C,  off, 64);
    }
    if (lane == 0) { partH[blk] = Hs; partC[blk] = C; }
  }
  __syncthreads();                   // sidx/hist ready; red dead

  for (int i = tid; i < CS; i += 256) hist_part[(size_t)blk*CS + i] = hist[i];

  // phase C: out-projection: gather table rows -> LDS -> coalesced writes
  for (int chunk = 0; chunk < 4; ++chunk) {
    for (int it = 0; it < 32; ++it) {
      int f = tid + it * 256;
      int r = f >> 7, c = f & 127;
      rows[r*129 + c] = table[(size_t)sidx[r]*D_ + chunk*128 + c];
    }
    __syncthreads();
    size_t base = ((size_t)b * D_ + chunk*128) * T_ + t0;
    for (int it = 0; it < 32; ++it) {
      int f = tid + it * 256;
      int t = f & 63, dd = f >> 6;
      out[base + (size_t)dd * T_ + t] = rows[t*129 + dd];
    }
    __syncthreads();
  }
}

// ---------------------------------------------------------------- reductions
__global__ __launch_bounds__(256) void hist_reduce(
    const float* __restrict__ hist_part, float* __restrict__ hmid)
{
  int r  = blockIdx.x >> 2;          // 0..31
  int bg = blockIdx.x & 3;
  int bin = bg * 256 + threadIdx.x;
  float s = 0.f;
  for (int m = 0; m < 32; ++m) s += hist_part[(size_t)(r*32 + m)*CS + bin];
  hmid[r*CS + bin] = s;
}

__global__ __launch_bounds__(256) void finalize(
    const float* __restrict__ hmid, const float* __restrict__ partH,
    const float* __restrict__ partC, float* __restrict__ aux_out)
{
  int tid = threadIdx.x;
  float ce = 0.f, h = 0.f, cm = 0.f;
  for (int q = 0; q < 4; ++q) {
    int bin = q*256 + tid;
    float s = 0.f;
    for (int r = 0; r < 32; ++r) s += hmid[r*CS + bin];
    float ap = s * (1.f/65536.f);
    ce += -ap * __logf(fmaxf(ap, 1e-5f));
  }
  for (int i = tid; i < 1024; i += 256) { h += partH[i]; cm += partC[i]; }
  __shared__ float rb[3][256];
  rb[0][tid] = ce; rb[1][tid] = h; rb[2][tid] = cm;
  __syncthreads();
  for (int s = 128; s > 0; s >>= 1) {
    if (tid < s) {
      rb[0][tid] += rb[0][tid+s];
      rb[1][tid] += rb[1][tid+s];
      rb[2][tid] += rb[2][tid+s];
    }
    __syncthreads();
  }
  if (tid == 0) {
    float psH    = rb[1][0] * (1.f/65536.f);
    float commit = rb[2][0] * (1.f/655360.f);
    aux_out[0] = psH - rb[0][0] + commit;
  }
}

// ---------------------------------------------------------------- launch
extern "C" void kernel_launch(void* const* d_in, const int* in_sizes, int n_in,
                              void* d_out, int out_size, void* d_ws, size_t ws_size,
                              hipStream_t stream) {
  const float* x     = (const float*)d_in[0];
  const float* in_v  = (const float*)d_in[1];
  const float* in_g  = (const float*)d_in[2];
  const float* in_b  = (const float*)d_in[3];
  const float* out_v = (const float*)d_in[4];
  const float* out_g = (const float*)d_in[5];
  const float* out_b = (const float*)d_in[6];

  float* out     = (float*)d_out;                    // 16*512*4096
  float* out_idx = out + (size_t)B_*D_*T_;           // 65536 (indices as f32)
  float* aux     = out_idx + NTOK;                   // 1

  float* wsf = (float*)d_ws;

  prep_w<<<dim3(1), dim3(256), 0, stream>>>(in_v, in_g, out_v, out_g,
                                            wsf + WS_WIN, wsf + WS_WOUT);
  build_table<<<dim3(CS), dim3(512), 0, stream>>>(wsf + WS_WOUT, out_b,
                                                  wsf + WS_TABLE);
  lfq_main<<<dim3(NBLK_MAIN), dim3(256), 0, stream>>>(
      x, in_b, wsf + WS_WIN, wsf + WS_TABLE,
      out, out_idx, wsf + WS_PARTH, wsf + WS_PARTC, wsf + WS_HIST);
  hist_reduce<<<dim3(128), dim3(256), 0, stream>>>(wsf + WS_HIST, wsf + WS_HMID);
  finalize<<<dim3(1), dim3(256), 0, stream>>>(wsf + WS_HMID, wsf + WS_PARTH,
                                              wsf + WS_PARTC, aux);
}

// Round 2
// 88.890 us; speedup vs baseline: 1.8170x; 1.8170x over previous
//
#include <hip/hip_runtime.h>
#include <math.h>

#define B_   16
#define D_   512
#define T_   4096
#define CD   10
#define CS   1024
#define NTOK (B_*T_)              // 65536
#define TPB_A 128                 // tokens per block, kernel A
#define NBLK_A (NTOK/TPB_A)       // 512
#define TPB_B 64                  // tokens per block, kernel B
#define NBLK_B (NTOK/TPB_B)       // 1024

// ws layout (float offsets)
#define WS_WIN    0               // 5120
#define WS_WOUT   5120            // 5120
#define WS_TABLE  10240           // 1024*512 = 524288
#define WS_PARTH  534528          // 1024
#define WS_PARTC  535552          // 1024
#define WS_IDXI   536576          // 65536 (int)
#define WS_HIST   602112          // 512*1024 = 524288
#define WS_HMID   1126400         // 32*1024

// ---------------------------------------------------------------- prep
__global__ __launch_bounds__(256) void prep_w(
    const float* __restrict__ in_v, const float* __restrict__ in_g,
    const float* __restrict__ out_v, const float* __restrict__ out_g,
    float* __restrict__ w_in, float* __restrict__ w_out)
{
  __shared__ double pn[160];
  __shared__ float nrm[CD];
  int tid = threadIdx.x;
  if (tid < 160) {
    int d = tid >> 4, j = tid & 15;
    double s = 0.0;
    const float* vp = in_v + d*D_ + j*32;
    #pragma unroll
    for (int k = 0; k < 32; ++k) { double v = (double)vp[k]; s += v*v; }
    pn[tid] = s;
  }
  __syncthreads();
  if (tid < CD) {
    double s = 0.0;
    #pragma unroll
    for (int j = 0; j < 16; ++j) s += pn[tid*16 + j];
    nrm[tid] = (float)sqrt(s);
  }
  __syncthreads();
  for (int i = tid; i < CD*D_; i += 256) {
    int d = i >> 9;
    w_in[i] = in_g[d] * in_v[i] / nrm[d];
  }
  for (int r = tid; r < D_; r += 256) {
    float s = 0.f;
    #pragma unroll
    for (int d = 0; d < CD; ++d) { float v = out_v[r*CD + d]; s += v*v; }
    float sc = out_g[r] / sqrtf(s);
    #pragma unroll
    for (int d = 0; d < CD; ++d) w_out[r*CD + d] = out_v[r*CD + d] * sc;
  }
}

// Table[j][D] = out_b[D] + sum_d w_out[D][d] * (+-1 per bit (9-d) of j)
__global__ __launch_bounds__(512) void build_table(
    const float* __restrict__ w_out, const float* __restrict__ out_b,
    float* __restrict__ table)
{
  int j = blockIdx.x;
  int D = threadIdx.x;
  const float* wr = w_out + D*CD;
  float s = out_b[D];
  #pragma unroll
  for (int d = 0; d < CD; ++d) {
    float sg = ((j >> (9 - d)) & 1) ? 1.f : -1.f;
    s += wr[d] * sg;
  }
  table[(size_t)j*D_ + D] = s;
}

// ------------------------------------------------- kernel A: in-proj + stats
__global__ __launch_bounds__(256) void lfq_proj(
    const float* __restrict__ x, const float* __restrict__ in_b,
    const float* __restrict__ w_in,
    float* __restrict__ out_idx, int* __restrict__ idx_int,
    float* __restrict__ partH, float* __restrict__ partC,
    float* __restrict__ hist_part)
{
  __shared__ float hist[CS];
  __shared__ double red[4*TPB_A*CD];   // 40960 B; first 20KB doubles as wT
  float* wT = (float*)red;

  const int tid  = threadIdx.x;
  const int blk  = blockIdx.x;
  const int b    = blk >> 5;
  const int t0   = (blk & 31) * TPB_A;
  const int wave = tid >> 6, lane = tid & 63;

  for (int i = tid; i < CS; i += 256) hist[i] = 0.f;
  for (int i = tid; i < CD*D_; i += 256) {
    // w_in is [d][D]; stage transposed wT[D][d]
    wT[(i & 511) * CD + (i >> 9)] = w_in[i];
  }
  __syncthreads();

  // phase A: f64 accumulate. wave = 128-D slice, lane = 2 tokens (float2).
  double acc[2*CD];
  #pragma unroll
  for (int i = 0; i < 2*CD; ++i) acc[i] = 0.0;
  const float* xb = x + ((size_t)b * D_) * T_ + t0 + 2*lane;
  const int D0 = wave * 128;
  #pragma unroll 4
  for (int Di = 0; Di < 128; ++Di) {
    int D = D0 + Di;
    float2 xv = *(const float2*)(xb + (size_t)D * T_);
    double x0 = (double)xv.x, x1 = (double)xv.y;
    const float2* w2 = (const float2*)(wT + D * CD);
    #pragma unroll
    for (int i = 0; i < 5; ++i) {
      float2 w = w2[i];
      acc[4*i+0] += (double)w.x * x0;   // dim 2i,   tok 0
      acc[4*i+1] += (double)w.x * x1;   // dim 2i,   tok 1
      acc[4*i+2] += (double)w.y * x0;   // dim 2i+1, tok 0
      acc[4*i+3] += (double)w.y * x1;   // dim 2i+1, tok 1
    }
  }
  __syncthreads();                     // wT dead; red takes over
  #pragma unroll
  for (int d = 0; d < CD; ++d) {
    red[((size_t)wave*TPB_A + 2*lane + 0)*CD + d] = acc[2*d+0];
    red[((size_t)wave*TPB_A + 2*lane + 1)*CD + d] = acc[2*d+1];
  }
  __syncthreads();

  // phase B: per-token quantize / entropy / histogram (waves 0,1)
  if (wave < 2) {
    const int ti = wave*64 + lane;
    float Hs = 0.f, C = 0.f;
    int   idx = 0;
    int   k = 0; int pos[CD]; float ms[CD];
    #pragma unroll
    for (int d = 0; d < CD; ++d) {
      double o = red[(size_t)(0*TPB_A + ti)*CD + d]
               + red[(size_t)(1*TPB_A + ti)*CD + d]
               + red[(size_t)(2*TPB_A + ti)*CD + d]
               + red[(size_t)(3*TPB_A + ti)*CD + d]
               + (double)in_b[d];
      float v = (float)o;
      int bit = (v > 0.f);
      idx |= bit << (9 - d);
      float c = v - (bit ? 1.f : -1.f);
      C += c * c;
      float e = __expf(-400.f * fabsf(v));   // exp(-|delta logit|)
      if (e > 1e-9f) { ms[k] = e / (1.f + e); pos[k] = 9 - d; ++k; }
    }
    int nc = 1 << k;
    for (int c = 0; c < nc; ++c) {
      float p = 1.f; int bin = idx;
      for (int i = 0; i < k; ++i) {
        if ((c >> i) & 1) { p *= ms[i]; bin ^= (1 << pos[i]); }
        else              { p *= (1.f - ms[i]); }
      }
      Hs -= p * __logf(fmaxf(p, 1e-5f));
      atomicAdd(&hist[bin], p);
    }
    out_idx[b * T_ + t0 + ti] = (float)idx;
    idx_int[b * T_ + t0 + ti] = idx;
    #pragma unroll
    for (int off = 32; off > 0; off >>= 1) {
      Hs += __shfl_down(Hs, off, 64);
      C  += __shfl_down(C,  off, 64);
    }
    if (lane == 0) { partH[blk*2 + wave] = Hs; partC[blk*2 + wave] = C; }
  }
  __syncthreads();

  for (int i = tid; i < CS; i += 256) hist_part[(size_t)blk*CS + i] = hist[i];
}

// ------------------------------------------------- kernel B: gather out-proj
__global__ __launch_bounds__(256) void lfq_out(
    const int* __restrict__ idx_int, const float* __restrict__ table,
    float* __restrict__ out)
{
  __shared__ float rows[TPB_B * 65];   // 16640 B, pad 65 -> 2-way max
  __shared__ int   sidx[TPB_B];

  const int tid = threadIdx.x;
  const int blk = blockIdx.x;
  const int b   = blk >> 6;
  const int t0  = (blk & 63) * TPB_B;

  if (tid < TPB_B) sidx[tid] = idx_int[b * T_ + t0 + tid];
  __syncthreads();

  #pragma unroll 1
  for (int ch = 0; ch < 8; ++ch) {
    #pragma unroll
    for (int i = 0; i < 4; ++i) {
      int f = tid + i*256;
      int r = f >> 4, c4 = (f & 15) * 4;
      float4 v = *(const float4*)(table + (size_t)sidx[r]*D_ + ch*64 + c4);
      rows[r*65 + c4 + 0] = v.x;
      rows[r*65 + c4 + 1] = v.y;
      rows[r*65 + c4 + 2] = v.z;
      rows[r*65 + c4 + 3] = v.w;
    }
    __syncthreads();
    #pragma unroll
    for (int i = 0; i < 4; ++i) {
      int f = tid + i*256;
      int dd = f >> 4, t4 = (f & 15) * 4;
      float4 o;
      o.x = rows[(t4+0)*65 + dd];
      o.y = rows[(t4+1)*65 + dd];
      o.z = rows[(t4+2)*65 + dd];
      o.w = rows[(t4+3)*65 + dd];
      *(float4*)(out + ((size_t)b*D_ + ch*64 + dd)*T_ + t0 + t4) = o;
    }
    __syncthreads();
  }
}

// ---------------------------------------------------------------- reductions
__global__ __launch_bounds__(256) void hist_reduce(
    const float* __restrict__ hist_part, float* __restrict__ hmid)
{
  int r  = blockIdx.x >> 2;          // 0..31
  int bg = blockIdx.x & 3;
  int bin = bg * 256 + threadIdx.x;
  float s = 0.f;
  for (int m = 0; m < 16; ++m) s += hist_part[(size_t)(r*16 + m)*CS + bin];
  hmid[r*CS + bin] = s;
}

__global__ __launch_bounds__(256) void finalize(
    const float* __restrict__ hmid, const float* __restrict__ partH,
    const float* __restrict__ partC, float* __restrict__ aux_out)
{
  int tid = threadIdx.x;
  float ce = 0.f, h = 0.f, cm = 0.f;
  for (int q = 0; q < 4; ++q) {
    int bin = q*256 + tid;
    float s = 0.f;
    for (int r = 0; r < 32; ++r) s += hmid[r*CS + bin];
    float ap = s * (1.f/65536.f);
    ce += -ap * __logf(fmaxf(ap, 1e-5f));
  }
  for (int i = tid; i < 1024; i += 256) { h += partH[i]; cm += partC[i]; }
  __shared__ float rb[3][256];
  rb[0][tid] = ce; rb[1][tid] = h; rb[2][tid] = cm;
  __syncthreads();
  for (int s = 128; s > 0; s >>= 1) {
    if (tid < s) {
      rb[0][tid] += rb[0][tid+s];
      rb[1][tid] += rb[1][tid+s];
      rb[2][tid] += rb[2][tid+s];
    }
    __syncthreads();
  }
  if (tid == 0) {
    float psH    = rb[1][0] * (1.f/65536.f);
    float commit = rb[2][0] * (1.f/655360.f);
    aux_out[0] = psH - rb[0][0] + commit;
  }
}

// ---------------------------------------------------------------- launch
extern "C" void kernel_launch(void* const* d_in, const int* in_sizes, int n_in,
                              void* d_out, int out_size, void* d_ws, size_t ws_size,
                              hipStream_t stream) {
  const float* x     = (const float*)d_in[0];
  const float* in_v  = (const float*)d_in[1];
  const float* in_g  = (const float*)d_in[2];
  const float* in_b  = (const float*)d_in[3];
  const float* out_v = (const float*)d_in[4];
  const float* out_g = (const float*)d_in[5];
  const float* out_b = (const float*)d_in[6];

  float* out     = (float*)d_out;                    // 16*512*4096
  float* out_idx = out + (size_t)B_*D_*T_;           // 65536 (indices as f32)
  float* aux     = out_idx + NTOK;                   // 1

  float* wsf = (float*)d_ws;

  prep_w<<<dim3(1), dim3(256), 0, stream>>>(in_v, in_g, out_v, out_g,
                                            wsf + WS_WIN, wsf + WS_WOUT);
  build_table<<<dim3(CS), dim3(512), 0, stream>>>(wsf + WS_WOUT, out_b,
                                                  wsf + WS_TABLE);
  lfq_proj<<<dim3(NBLK_A), dim3(256), 0, stream>>>(
      x, in_b, wsf + WS_WIN,
      out_idx, (int*)(wsf + WS_IDXI),
      wsf + WS_PARTH, wsf + WS_PARTC, wsf + WS_HIST);
  lfq_out<<<dim3(NBLK_B), dim3(256), 0, stream>>>(
      (const int*)(wsf + WS_IDXI), wsf + WS_TABLE, out);
  hist_reduce<<<dim3(128), dim3(256), 0, stream>>>(wsf + WS_HIST, wsf + WS_HMID);
  finalize<<<dim3(1), dim3(256), 0, stream>>>(wsf + WS_HMID, wsf + WS_PARTH,
                                              wsf + WS_PARTC, aux);
}

// Round 3
// 81.079 us; speedup vs baseline: 1.9920x; 1.0963x over previous
//
#include <hip/hip_runtime.h>
#include <math.h>

#define B_   16
#define D_   512
#define T_   4096
#define CD   10
#define CS   1024
#define NTOK (B_*T_)              // 65536
#define TPB_A 128                 // tokens per block, kernel A
#define NBLK_A (NTOK/TPB_A)       // 512
#define TPB_B 64                  // tokens per block, kernel B
#define NBLK_B (NTOK/TPB_B)       // 1024

// ws layout (float offsets)
#define WS_WT     0               // 5120  (w_t[D][d], transposed, normalized)
#define WS_TABLE  5120            // 1024*512 = 524288
#define WS_PARTH  529408          // 1024
#define WS_PARTC  530432          // 1024
#define WS_IDXI   531456          // 65536 (int)
#define WS_HIST   596992          // 512*1024 = 524288
#define WS_HMID   1121280         // 32*1024

// --------------------------------------------- prep: transposed w_in
// 10 blocks, block d: norm over in_v[d,:], write w_t[D*10+d].
// f32 arithmetic order identical to the validated R1/R2 version.
__global__ __launch_bounds__(256) void prep_wt(
    const float* __restrict__ in_v, const float* __restrict__ in_g,
    float* __restrict__ w_t)
{
  __shared__ double pn[16];
  __shared__ float nrm_s;
  const int d   = blockIdx.x;
  const int tid = threadIdx.x;
  if (tid < 16) {
    double s = 0.0;
    const float* vp = in_v + d*D_ + tid*32;
    #pragma unroll
    for (int k = 0; k < 32; ++k) { double v = (double)vp[k]; s += v*v; }
    pn[tid] = s;
  }
  __syncthreads();
  if (tid == 0) {
    double s = 0.0;
    #pragma unroll
    for (int j = 0; j < 16; ++j) s += pn[j];
    nrm_s = (float)sqrt(s);
  }
  __syncthreads();
  const float g = in_g[d], nrm = nrm_s;
  for (int D = tid; D < D_; D += 256)
    w_t[D*CD + d] = g * in_v[d*D_ + D] / nrm;
}

// Table[j][D] = out_b[D] + sum_d w_out[D][d] * (+-1 per bit (9-d) of j)
// w_out derived in-kernel (same f32 order as validated version).
__global__ __launch_bounds__(512) void build_table(
    const float* __restrict__ out_v, const float* __restrict__ out_g,
    const float* __restrict__ out_b, float* __restrict__ table)
{
  int j = blockIdx.x;
  int D = threadIdx.x;
  const float* vr = out_v + D*CD;
  float vv[CD];
  float s2 = 0.f;
  #pragma unroll
  for (int d = 0; d < CD; ++d) { vv[d] = vr[d]; s2 += vv[d]*vv[d]; }
  const float sc = out_g[D] / sqrtf(s2);
  float s = out_b[D];
  #pragma unroll
  for (int d = 0; d < CD; ++d) {
    float sg = ((j >> (9 - d)) & 1) ? 1.f : -1.f;
    s += (vv[d] * sc) * sg;
  }
  table[(size_t)j*D_ + D] = s;
}

// ------------------------------------------------- kernel A: in-proj + stats
__global__ __launch_bounds__(256) void lfq_proj(
    const float* __restrict__ x, const float* __restrict__ in_b,
    const float* __restrict__ w_t,
    float* __restrict__ out_idx, int* __restrict__ idx_int,
    float* __restrict__ partH, float* __restrict__ partC,
    float* __restrict__ hist_part)
{
  __shared__ float hist[CS];
  __shared__ double red[4*TPB_A*CD];   // 40960 B

  const int tid  = threadIdx.x;
  const int blk  = blockIdx.x;
  const int b    = blk >> 5;
  const int t0   = (blk & 31) * TPB_A;
  const int wave = __builtin_amdgcn_readfirstlane(tid >> 6);
  const int lane = tid & 63;

  for (int i = tid; i < CS; i += 256) hist[i] = 0.f;

  // phase A: f64 accumulate. wave = 128-D slice, lane = 2 tokens (float2).
  // weight addresses are wave-uniform -> scalar (SMEM) loads.
  double acc[2*CD];
  #pragma unroll
  for (int i = 0; i < 2*CD; ++i) acc[i] = 0.0;
  const float* xb = x + ((size_t)b * D_) * T_ + t0 + 2*lane;
  const float* wp = w_t + (size_t)wave * 128 * CD;
  #pragma unroll 4
  for (int Di = 0; Di < 128; ++Di) {
    float2 xv = *(const float2*)(xb + (size_t)(wave*128 + Di) * T_);
    double x0 = (double)xv.x, x1 = (double)xv.y;
    const float2* w2 = (const float2*)(wp + Di * CD);
    #pragma unroll
    for (int i = 0; i < 5; ++i) {
      float2 w = w2[i];
      acc[4*i+0] += (double)w.x * x0;
      acc[4*i+1] += (double)w.x * x1;
      acc[4*i+2] += (double)w.y * x0;
      acc[4*i+3] += (double)w.y * x1;
    }
  }
  __syncthreads();                     // hist init done; red writes begin
  #pragma unroll
  for (int d = 0; d < CD; ++d) {
    red[((size_t)wave*TPB_A + 2*lane + 0)*CD + d] = acc[2*d+0];
    red[((size_t)wave*TPB_A + 2*lane + 1)*CD + d] = acc[2*d+1];
  }
  __syncthreads();

  // phase B: per-token quantize / entropy / histogram (waves 0,1)
  if (wave < 2) {
    const int ti = wave*64 + lane;
    float Hs = 0.f, C = 0.f;
    int   idx = 0;
    int   k = 0; int pos[CD]; float ms[CD];
    #pragma unroll
    for (int d = 0; d < CD; ++d) {
      double o = red[(size_t)(0*TPB_A + ti)*CD + d]
               + red[(size_t)(1*TPB_A + ti)*CD + d]
               + red[(size_t)(2*TPB_A + ti)*CD + d]
               + red[(size_t)(3*TPB_A + ti)*CD + d]
               + (double)in_b[d];
      float v = (float)o;
      int bit = (v > 0.f);
      idx |= bit << (9 - d);
      float c = v - (bit ? 1.f : -1.f);
      C += c * c;
      float e = __expf(-400.f * fabsf(v));   // exp(-|delta logit|)
      if (e > 1e-9f) { ms[k] = e / (1.f + e); pos[k] = 9 - d; ++k; }
    }
    int nc = 1 << k;
    for (int c = 0; c < nc; ++c) {
      float p = 1.f; int bin = idx;
      for (int i = 0; i < k; ++i) {
        if ((c >> i) & 1) { p *= ms[i]; bin ^= (1 << pos[i]); }
        else              { p *= (1.f - ms[i]); }
      }
      Hs -= p * __logf(fmaxf(p, 1e-5f));
      atomicAdd(&hist[bin], p);
    }
    out_idx[b * T_ + t0 + ti] = (float)idx;
    idx_int[b * T_ + t0 + ti] = idx;
    #pragma unroll
    for (int off = 32; off > 0; off >>= 1) {
      Hs += __shfl_down(Hs, off, 64);
      C  += __shfl_down(C,  off, 64);
    }
    if (lane == 0) { partH[blk*2 + wave] = Hs; partC[blk*2 + wave] = C; }
  }
  __syncthreads();

  for (int i = tid; i < CS; i += 256) hist_part[(size_t)blk*CS + i] = hist[i];
}

// ------------------------------------------------- kernel B: gather out-proj
__global__ __launch_bounds__(256) void lfq_out(
    const int* __restrict__ idx_int, const float* __restrict__ table,
    float* __restrict__ out)
{
  __shared__ float rows[TPB_B * 65];   // 16640 B, pad 65 -> 2-way max
  __shared__ int   sidx[TPB_B];

  const int tid = threadIdx.x;
  const int blk = blockIdx.x;
  const int b   = blk >> 6;
  const int t0  = (blk & 63) * TPB_B;

  if (tid < TPB_B) sidx[tid] = idx_int[b * T_ + t0 + tid];
  __syncthreads();

  #pragma unroll 1
  for (int ch = 0; ch < 8; ++ch) {
    #pragma unroll
    for (int i = 0; i < 4; ++i) {
      int f = tid + i*256;
      int r = f >> 4, c4 = (f & 15) * 4;
      float4 v = *(const float4*)(table + (size_t)sidx[r]*D_ + ch*64 + c4);
      rows[r*65 + c4 + 0] = v.x;
      rows[r*65 + c4 + 1] = v.y;
      rows[r*65 + c4 + 2] = v.z;
      rows[r*65 + c4 + 3] = v.w;
    }
    __syncthreads();
    #pragma unroll
    for (int i = 0; i < 4; ++i) {
      int f = tid + i*256;
      int dd = f >> 4, t4 = (f & 15) * 4;
      float4 o;
      o.x = rows[(t4+0)*65 + dd];
      o.y = rows[(t4+1)*65 + dd];
      o.z = rows[(t4+2)*65 + dd];
      o.w = rows[(t4+3)*65 + dd];
      *(float4*)(out + ((size_t)b*D_ + ch*64 + dd)*T_ + t0 + t4) = o;
    }
    __syncthreads();
  }
}

// ---------------------------------------------------------------- reductions
__global__ __launch_bounds__(256) void hist_reduce(
    const float* __restrict__ hist_part, float* __restrict__ hmid)
{
  int r  = blockIdx.x >> 2;          // 0..31
  int bg = blockIdx.x & 3;
  int bin = bg * 256 + threadIdx.x;
  float s = 0.f;
  for (int m = 0; m < 16; ++m) s += hist_part[(size_t)(r*16 + m)*CS + bin];
  hmid[r*CS + bin] = s;
}

__global__ __launch_bounds__(256) void finalize(
    const float* __restrict__ hmid, const float* __restrict__ partH,
    const float* __restrict__ partC, float* __restrict__ aux_out)
{
  int tid = threadIdx.x;
  float ce = 0.f, h = 0.f, cm = 0.f;
  for (int q = 0; q < 4; ++q) {
    int bin = q*256 + tid;
    float s = 0.f;
    for (int r = 0; r < 32; ++r) s += hmid[r*CS + bin];
    float ap = s * (1.f/65536.f);
    ce += -ap * __logf(fmaxf(ap, 1e-5f));
  }
  for (int i = tid; i < 1024; i += 256) { h += partH[i]; cm += partC[i]; }
  __shared__ float rb[3][256];
  rb[0][tid] = ce; rb[1][tid] = h; rb[2][tid] = cm;
  __syncthreads();
  for (int s = 128; s > 0; s >>= 1) {
    if (tid < s) {
      rb[0][tid] += rb[0][tid+s];
      rb[1][tid] += rb[1][tid+s];
      rb[2][tid] += rb[2][tid+s];
    }
    __syncthreads();
  }
  if (tid == 0) {
    float psH    = rb[1][0] * (1.f/65536.f);
    float commit = rb[2][0] * (1.f/655360.f);
    aux_out[0] = psH - rb[0][0] + commit;
  }
}

// ---------------------------------------------------------------- launch
extern "C" void kernel_launch(void* const* d_in, const int* in_sizes, int n_in,
                              void* d_out, int out_size, void* d_ws, size_t ws_size,
                              hipStream_t stream) {
  const float* x     = (const float*)d_in[0];
  const float* in_v  = (const float*)d_in[1];
  const float* in_g  = (const float*)d_in[2];
  const float* in_b  = (const float*)d_in[3];
  const float* out_v = (const float*)d_in[4];
  const float* out_g = (const float*)d_in[5];
  const float* out_b = (const float*)d_in[6];

  float* out     = (float*)d_out;                    // 16*512*4096
  float* out_idx = out + (size_t)B_*D_*T_;           // 65536 (indices as f32)
  float* aux     = out_idx + NTOK;                   // 1

  float* wsf = (float*)d_ws;

  prep_wt<<<dim3(CD), dim3(256), 0, stream>>>(in_v, in_g, wsf + WS_WT);
  lfq_proj<<<dim3(NBLK_A), dim3(256), 0, stream>>>(
      x, in_b, wsf + WS_WT,
      out_idx, (int*)(wsf + WS_IDXI),
      wsf + WS_PARTH, wsf + WS_PARTC, wsf + WS_HIST);
  build_table<<<dim3(CS), dim3(512), 0, stream>>>(out_v, out_g, out_b,
                                                  wsf + WS_TABLE);
  lfq_out<<<dim3(NBLK_B), dim3(256), 0, stream>>>(
      (const int*)(wsf + WS_IDXI), wsf + WS_TABLE, out);
  hist_reduce<<<dim3(128), dim3(256), 0, stream>>>(wsf + WS_HIST, wsf + WS_HMID);
  finalize<<<dim3(1), dim3(256), 0, stream>>>(wsf + WS_HMID, wsf + WS_PARTH,
                                              wsf + WS_PARTC, aux);
}

// Round 5
// 64.833 us; speedup vs baseline: 2.4912x; 1.2506x over previous
//
#include <hip/hip_runtime.h>
#include <math.h>

#define B_   16
#define D_   512
#define T_   4096
#define CD   10
#define CS   1024
#define NTOK (B_*T_)              // 65536
#define TPB_A 128                 // tokens per block, fused kernel
#define NBLK_A (NTOK/TPB_A)       // 512

typedef float f32x2 __attribute__((ext_vector_type(2)));
typedef float f32x4 __attribute__((ext_vector_type(4)));

// ws layout (float offsets)
#define WS_WT     0               // 5120  (w_t[D][d], transposed, normalized)
#define WS_PARTH  5120            // 1024
#define WS_PARTC  6144            // 1024
#define WS_HIST   7168            // 512*1024 = 524288
#define WS_HMID   531456          // 32*1024

// --------------------------------------------- prep: transposed w_in
// 10 blocks, block d: norm over in_v[d,:], write w_t[D*10+d].
// f32/f64 arithmetic order identical to the validated R3 version.
__global__ __launch_bounds__(256) void prep_wt(
    const float* __restrict__ in_v, const float* __restrict__ in_g,
    float* __restrict__ w_t)
{
  __shared__ double pn[16];
  __shared__ float nrm_s;
  const int d   = blockIdx.x;
  const int tid = threadIdx.x;
  if (tid < 16) {
    double s = 0.0;
    const float* vp = in_v + d*D_ + tid*32;
    #pragma unroll
    for (int k = 0; k < 32; ++k) { double v = (double)vp[k]; s += v*v; }
    pn[tid] = s;
  }
  __syncthreads();
  if (tid == 0) {
    double s = 0.0;
    #pragma unroll
    for (int j = 0; j < 16; ++j) s += pn[j];
    nrm_s = (float)sqrt(s);
  }
  __syncthreads();
  const float g = in_g[d], nrm = nrm_s;
  for (int D = tid; D < D_; D += 256)
    w_t[D*CD + d] = g * in_v[d*D_ + D] / nrm;
}

// ------------------------------------- fused: in-proj + stats + out-proj
__global__ __launch_bounds__(256) void lfq_fused(
    const float* __restrict__ x, const float* __restrict__ in_b,
    const float* __restrict__ w_t,
    const float* __restrict__ out_v, const float* __restrict__ out_g,
    const float* __restrict__ out_b,
    float* __restrict__ out, float* __restrict__ out_idx,
    float* __restrict__ partH, float* __restrict__ partC,
    float* __restrict__ hist_part)
{
  __shared__ float  hist[CS];            // 4 KB
  __shared__ int    sidx[TPB_A];         // 512 B
  __shared__ double red[4*TPB_A*CD];     // 40 KB
  __shared__ float  wn[D_*CD];           // 20 KB  (normalized w_out, [D][d])
  __shared__ float  ob[D_];              // 2 KB

  const int tid  = threadIdx.x;
  const int blk  = blockIdx.x;
  const int b    = blk >> 5;
  const int t0   = (blk & 31) * TPB_A;
  const int wave = __builtin_amdgcn_readfirstlane(tid >> 6);
  const int lane = tid & 63;

  for (int i = tid; i < CS; i += 256) hist[i] = 0.f;

  // phase A: f64 in-proj. wave = 128-D slice, lane = 2 tokens (float2).
  // weight addresses wave-uniform -> scalar (SMEM) loads.
  double acc[2*CD];
  #pragma unroll
  for (int i = 0; i < 2*CD; ++i) acc[i] = 0.0;
  const float* xb = x + ((size_t)b * D_ + wave * 128) * T_ + t0 + 2*lane;
  const float* wp = w_t + (size_t)wave * 128 * CD;
  #pragma unroll 8
  for (int Di = 0; Di < 128; ++Di) {
    f32x2 xv = __builtin_nontemporal_load(
                    (const f32x2*)(xb + (size_t)Di * T_));
    double x0 = (double)xv.x, x1 = (double)xv.y;
    const f32x2* w2 = (const f32x2*)(wp + Di * CD);
    #pragma unroll
    for (int i = 0; i < 5; ++i) {
      f32x2 w = w2[i];
      acc[4*i+0] += (double)w.x * x0;
      acc[4*i+1] += (double)w.x * x1;
      acc[4*i+2] += (double)w.y * x0;
      acc[4*i+3] += (double)w.y * x1;
    }
  }
  #pragma unroll
  for (int d = 0; d < CD; ++d) {
    red[((size_t)wave*TPB_A + 2*lane + 0)*CD + d] = acc[2*d+0];
    red[((size_t)wave*TPB_A + 2*lane + 1)*CD + d] = acc[2*d+1];
  }
  __syncthreads();

  // phase B: waves 0,1 -> quantize / entropy / histogram;
  //          waves 2,3 -> stage normalized w_out into LDS (build_table order)
  if (wave < 2) {
    const int ti = wave*64 + lane;
    float Hs = 0.f, C = 0.f;
    int   idx = 0;
    int   k = 0; int pos[CD]; float ms[CD];
    #pragma unroll
    for (int d = 0; d < CD; ++d) {
      double o = red[(size_t)(0*TPB_A + ti)*CD + d]
               + red[(size_t)(1*TPB_A + ti)*CD + d]
               + red[(size_t)(2*TPB_A + ti)*CD + d]
               + red[(size_t)(3*TPB_A + ti)*CD + d]
               + (double)in_b[d];
      float v = (float)o;
      int bit = (v > 0.f);
      idx |= bit << (9 - d);
      float c = v - (bit ? 1.f : -1.f);
      C += c * c;
      float e = __expf(-400.f * fabsf(v));   // exp(-|delta logit|)
      if (e > 1e-9f) { ms[k] = e / (1.f + e); pos[k] = 9 - d; ++k; }
    }
    int nc = 1 << k;
    for (int c = 0; c < nc; ++c) {
      float p = 1.f; int bin = idx;
      for (int i = 0; i < k; ++i) {
        if ((c >> i) & 1) { p *= ms[i]; bin ^= (1 << pos[i]); }
        else              { p *= (1.f - ms[i]); }
      }
      Hs -= p * __logf(fmaxf(p, 1e-5f));
      atomicAdd(&hist[bin], p);
    }
    out_idx[b * T_ + t0 + ti] = (float)idx;
    sidx[ti] = idx;
    #pragma unroll
    for (int off = 32; off > 0; off >>= 1) {
      Hs += __shfl_down(Hs, off, 64);
      C  += __shfl_down(C,  off, 64);
    }
    if (lane == 0) { partH[blk*2 + wave] = Hs; partC[blk*2 + wave] = C; }
  } else {
    const int local = tid - 128;           // 0..127, 4 D-rows each
    #pragma unroll
    for (int r = 0; r < 4; ++r) {
      const int D = local*4 + r;
      const float* vr = out_v + D*CD;
      float vv[CD];
      float s2 = 0.f;
      #pragma unroll
      for (int d = 0; d < CD; ++d) { vv[d] = vr[d]; s2 += vv[d]*vv[d]; }
      const float sc = out_g[D] / sqrtf(s2);
      #pragma unroll
      for (int d = 0; d < CD; ++d) wn[D*CD + d] = vv[d] * sc;
      ob[D] = out_b[D];
    }
  }
  __syncthreads();

  for (int i = tid; i < CS; i += 256) hist_part[(size_t)blk*CS + i] = hist[i];

  // phase C: direct out-projection. Thread owns 4 fixed tokens, walks 64 D.
  const int t4 = (tid & 31) * 4;
  const int c0 = sidx[t4+0], c1 = sidx[t4+1], c2 = sidx[t4+2], c3 = sidx[t4+3];
  const int Dbase = tid >> 5;
  float* op = out + ((size_t)b * D_) * T_ + t0 + t4;
  #pragma unroll 4
  for (int it = 0; it < 64; ++it) {
    const int D = Dbase + it*8;
    const float* wr = wn + D*CD;
    const float base = ob[D];
    float s0 = base, s1 = base, s2 = base, s3 = base;
    #pragma unroll
    for (int d = 0; d < CD; ++d) {
      const float w = wr[d];
      const int sh = 9 - d;
      s0 += ((c0 >> sh) & 1) ? w : -w;
      s1 += ((c1 >> sh) & 1) ? w : -w;
      s2 += ((c2 >> sh) & 1) ? w : -w;
      s3 += ((c3 >> sh) & 1) ? w : -w;
    }
    f32x4 o; o.x = s0; o.y = s1; o.z = s2; o.w = s3;
    __builtin_nontemporal_store(o, (f32x4*)(op + (size_t)D * T_));
  }
}

// ---------------------------------------------------------------- reductions
__global__ __launch_bounds__(256) void hist_reduce(
    const float* __restrict__ hist_part, float* __restrict__ hmid)
{
  int r  = blockIdx.x >> 2;          // 0..31
  int bg = blockIdx.x & 3;
  int bin = bg * 256 + threadIdx.x;
  float s = 0.f;
  for (int m = 0; m < 16; ++m) s += hist_part[(size_t)(r*16 + m)*CS + bin];
  hmid[r*CS + bin] = s;
}

__global__ __launch_bounds__(256) void finalize(
    const float* __restrict__ hmid, const float* __restrict__ partH,
    const float* __restrict__ partC, float* __restrict__ aux_out)
{
  int tid = threadIdx.x;
  float ce = 0.f, h = 0.f, cm = 0.f;
  for (int q = 0; q < 4; ++q) {
    int bin = q*256 + tid;
    float s = 0.f;
    for (int r = 0; r < 32; ++r) s += hmid[r*CS + bin];
    float ap = s * (1.f/65536.f);
    ce += -ap * __logf(fmaxf(ap, 1e-5f));
  }
  for (int i = tid; i < 1024; i += 256) { h += partH[i]; cm += partC[i]; }
  __shared__ float rb[3][256];
  rb[0][tid] = ce; rb[1][tid] = h; rb[2][tid] = cm;
  __syncthreads();
  for (int s = 128; s > 0; s >>= 1) {
    if (tid < s) {
      rb[0][tid] += rb[0][tid+s];
      rb[1][tid] += rb[1][tid+s];
      rb[2][tid] += rb[2][tid+s];
    }
    __syncthreads();
  }
  if (tid == 0) {
    float psH    = rb[1][0] * (1.f/65536.f);
    float commit = rb[2][0] * (1.f/655360.f);
    aux_out[0] = psH - rb[0][0] + commit;
  }
}

// ---------------------------------------------------------------- launch
extern "C" void kernel_launch(void* const* d_in, const int* in_sizes, int n_in,
                              void* d_out, int out_size, void* d_ws, size_t ws_size,
                              hipStream_t stream) {
  const float* x     = (const float*)d_in[0];
  const float* in_v  = (const float*)d_in[1];
  const float* in_g  = (const float*)d_in[2];
  const float* in_b  = (const float*)d_in[3];
  const float* out_v = (const float*)d_in[4];
  const float* out_g = (const float*)d_in[5];
  const float* out_b = (const float*)d_in[6];

  float* out     = (float*)d_out;                    // 16*512*4096
  float* out_idx = out + (size_t)B_*D_*T_;           // 65536 (indices as f32)
  float* aux     = out_idx + NTOK;                   // 1

  float* wsf = (float*)d_ws;

  prep_wt<<<dim3(CD), dim3(256), 0, stream>>>(in_v, in_g, wsf + WS_WT);
  lfq_fused<<<dim3(NBLK_A), dim3(256), 0, stream>>>(
      x, in_b, wsf + WS_WT, out_v, out_g, out_b,
      out, out_idx,
      wsf + WS_PARTH, wsf + WS_PARTC, wsf + WS_HIST);
  hist_reduce<<<dim3(128), dim3(256), 0, stream>>>(wsf + WS_HIST, wsf + WS_HMID);
  finalize<<<dim3(1), dim3(256), 0, stream>>>(wsf + WS_HMID, wsf + WS_PARTH,
                                              wsf + WS_PARTC, aux);
}